// Round 2
// baseline (439.945 us; speedup 1.0000x reference)
//
#include <hip/hip_runtime.h>
#include <hip/hip_bf16.h>

#define Bsz 256
#define Tsz 512
#define Hsz 256

typedef __attribute__((ext_vector_type(8))) short short8;
typedef __attribute__((ext_vector_type(4))) float f32x4;

static __device__ __forceinline__ float bf2f(unsigned short u) {
    union { unsigned int i; float f; } v; v.i = ((unsigned int)u) << 16; return v.f;
}
static __device__ __forceinline__ unsigned short f2bf(float f) {
    union { float f; unsigned int i; } v; v.f = f;
    unsigned int r = v.i + 0x7fffu + ((v.i >> 16) & 1u);   // RNE
    return (unsigned short)(r >> 16);
}

// Wave-uniform dtype probe: fp32 buffers have random mantissa low-halfwords
// whose bf16-exponent field is >=151 (|v|>2^23) with p~0.4 per element; sane
// bf16 data (N(0,1)-scale) never exceeds exponent ~130. P(miss) ~ 0.59^64.
static __device__ __forceinline__ bool probe_isbf16(const void* p) {
    unsigned int d = ((const unsigned int*)p)[threadIdx.x & 63];
    int e0 = (d >> 7) & 0xFF;
    int e1 = (d >> 23) & 0xFF;
    return !__any((e0 >= 151) || (e1 >= 151));
}

static __device__ __forceinline__ float ldE(const void* p, size_t i, bool isbf) {
    return isbf ? bf2f(((const unsigned short*)p)[i]) : ((const float*)p)[i];
}
static __device__ __forceinline__ void stE(void* p, size_t i, bool isbf, float v) {
    if (isbf) ((unsigned short*)p)[i] = f2bf(v);
    else      ((float*)p)[i] = v;
}
// load 8 consecutive elements as bf16x8 (16B-aligned i)
static __device__ __forceinline__ short8 ld8bf(const void* p, size_t i, bool isbf) {
    if (isbf) return *(const short8*)((const unsigned short*)p + i);
    const float4* q = (const float4*)((const float*)p + i);
    float4 a = q[0], b = q[1];
    short8 v;
    v[0] = (short)f2bf(a.x); v[1] = (short)f2bf(a.y); v[2] = (short)f2bf(a.z); v[3] = (short)f2bf(a.w);
    v[4] = (short)f2bf(b.x); v[5] = (short)f2bf(b.y); v[6] = (short)f2bf(b.z); v[7] = (short)f2bf(b.w);
    return v;
}

// ---------------- Phase 1: gates = sigmoid(x @ Wx^T + b) -> d_out -----------
// Tile M=64, N=64, K=256. 4 waves; wave w owns m-subtile w.
__global__ __launch_bounds__(256) void gates_kernel(
    const void* __restrict__ x, const void* __restrict__ Wxw,
    const void* __restrict__ Wxb, void* __restrict__ out)
{
    __shared__ __align__(16) unsigned short As[64 * 256];
    __shared__ __align__(16) unsigned short Ws[64 * 256];

    const bool isbf = probe_isbf16(x);
    const int tid  = threadIdx.x;
    const int bid  = blockIdx.x;
    const int n0   = (bid & 3) * 64;
    const int m0   = (bid >> 2) * 64;
    const int l    = tid & 63;
    const int w    = tid >> 6;
    const int lo16 = l & 15;
    const int hi   = l >> 4;

    // stage A(64x256) and W(64x256) as bf16, 16B chunks, XOR swizzle chunk^=(row&7)
#pragma unroll
    for (int i = 0; i < 8; ++i) {
        int c  = tid + i * 256;
        int m  = c >> 5;          // 32 chunks (of 8 elems) per row
        int cc = c & 31;
        int dst = m * 512 + ((cc ^ (m & 7)) << 4);
        *(short8*)((char*)As + dst) = ld8bf(x,   (size_t)(m0 + m) * 256 + cc * 8, isbf);
        *(short8*)((char*)Ws + dst) = ld8bf(Wxw, (size_t)(n0 + m) * 256 + cc * 8, isbf);
    }
    __syncthreads();

    // A fragments: LDS row = w*16+lo16, k = ks*32 + hi*8
    short8 af[8];
    {
        int row = w * 16 + lo16;
#pragma unroll
        for (int ks = 0; ks < 8; ++ks)
            af[ks] = *(const short8*)((const char*)As + row * 512 + (((ks * 4 + hi) ^ (row & 7)) << 4));
    }

    f32x4 acc[4];
#pragma unroll
    for (int nt = 0; nt < 4; ++nt) { f32x4 z = {0.f, 0.f, 0.f, 0.f}; acc[nt] = z; }

#pragma unroll
    for (int ks = 0; ks < 8; ++ks) {
#pragma unroll
        for (int nt = 0; nt < 4; ++nt) {
            int row = nt * 16 + lo16;
            short8 bf = *(const short8*)((const char*)Ws + row * 512 + (((ks * 4 + hi) ^ (row & 7)) << 4));
            acc[nt] = __builtin_amdgcn_mfma_f32_16x16x32_bf16(af[ks], bf, acc[nt], 0, 0, 0);
        }
    }

#pragma unroll
    for (int nt = 0; nt < 4; ++nt) {
        int   n    = n0 + nt * 16 + lo16;
        float bias = ldE(Wxb, n, isbf);
#pragma unroll
        for (int r = 0; r < 4; ++r) {
            int   m = m0 + w * 16 + hi * 4 + r;
            float z = acc[nt][r] + bias;
            float g = __builtin_amdgcn_rcpf(1.f + __expf(-z));  // 1/(1+inf)=0 handles underflow
            stE(out, (size_t)m * 256 + n, isbf, g);
        }
    }
}

// ---------------- Phase 2: sequential scan, 1 batch per block ----------------
// h_new = g*h + (1-g)*tanh(h @ Wh^T + b). Wh resident in registers as B-frags.
__global__ __launch_bounds__(256, 1) void scan_kernel(
    const void* __restrict__ Whw, const void* __restrict__ Whb,
    void* __restrict__ io)   // d_out: reads gates, overwrites with h
{
    __shared__ __align__(16) unsigned short hb[2][256];   // bf16 h, double-buffered

    const bool isbf = probe_isbf16(Whw);
    const int tid  = threadIdx.x;
    const int b    = blockIdx.x;
    const int l    = tid & 63;
    const int w    = tid >> 6;
    const int lo16 = l & 15;
    const int hi   = l >> 4;

    // B-fragments: lane holds B[k][n] = Wh[n][k], n = w*64+nt*16+lo16, k = ks*32+hi*8..+7
    short8 wf[4][8];
#pragma unroll
    for (int nt = 0; nt < 4; ++nt) {
        int n = w * 64 + nt * 16 + lo16;
#pragma unroll
        for (int ks = 0; ks < 8; ++ks)
            wf[nt][ks] = ld8bf(Whw, (size_t)n * 256 + ks * 32 + hi * 8, isbf);
    }
    float bias[4];
#pragma unroll
    for (int nt = 0; nt < 4; ++nt) bias[nt] = ldE(Whb, w * 64 + nt * 16 + lo16, isbf);

    hb[0][tid] = 0;          // h0 = 0 (bf16 0)
    float hreg = 0.f;        // this thread's own h column (fp32, exact blend state)

    const size_t rb = (size_t)b * Tsz * Hsz;
    // 3-deep register prefetch pipeline for g (covers ~900cy HBM latency)
    float g0 = ldE(io, rb +             tid, isbf);
    float g1 = ldE(io, rb +       Hsz + tid, isbf);
    float g2 = ldE(io, rb + 2UL * Hsz + tid, isbf);

    int p = 0;
    for (int t = 0; t < Tsz; ++t) {
        __syncthreads();                       // hb[p] (written last iter) visible

        float gp = (t + 3 < Tsz) ? ldE(io, rb + (size_t)(t + 3) * Hsz + tid, isbf) : 0.f;

        // A fragments from h broadcast (all 16 A-rows identical)
        short8 af[8];
#pragma unroll
        for (int ks = 0; ks < 8; ++ks)
            af[ks] = *(const short8*)(const void*)(&hb[p][ks * 32 + hi * 8]);

        f32x4 acc[4];
#pragma unroll
        for (int nt = 0; nt < 4; ++nt) { f32x4 z = {bias[nt], 0.f, 0.f, 0.f}; acc[nt] = z; }
#pragma unroll
        for (int ks = 0; ks < 8; ++ks) {
#pragma unroll
            for (int nt = 0; nt < 4; ++nt)
                acc[nt] = __builtin_amdgcn_mfma_f32_16x16x32_bf16(af[ks], wf[nt][ks], acc[nt], 0, 0, 0);
        }

        // acc[nt][0] = dot(n)+bias(n), n = w*64+nt*16+lo16; pick nt=hi so n == tid
        float z = (hi == 0) ? acc[0][0] : ((hi == 1) ? acc[1][0] : ((hi == 2) ? acc[2][0] : acc[3][0]));
        z = fminf(fmaxf(z, -15.f), 15.f);
        float ex = __expf(2.f * z);
        float th = (ex - 1.f) * __builtin_amdgcn_rcpf(ex + 1.f);
        float hn = g0 * hreg + (1.f - g0) * th;

        hreg = hn;
        hb[p ^ 1][tid] = f2bf(hn);             // next step's A operand
        stE(io, rb + (size_t)t * Hsz + tid, isbf, hn);

        g0 = g1; g1 = g2; g2 = gp;
        p ^= 1;
    }
}

extern "C" void kernel_launch(void* const* d_in, const int* in_sizes, int n_in,
                              void* d_out, int out_size, void* d_ws, size_t ws_size,
                              hipStream_t stream) {
    const void* x   = d_in[0];
    const void* Wxw = d_in[1];
    const void* Wxb = d_in[2];
    const void* Whw = d_in[3];
    const void* Whb = d_in[4];

    gates_kernel<<<dim3(8192), dim3(256), 0, stream>>>(x, Wxw, Wxb, d_out);
    scan_kernel<<<dim3(Bsz), dim3(256), 0, stream>>>(Whw, Whb, d_out);
}